// Round 3
// baseline (410.782 us; speedup 1.0000x reference)
//
#include <hip/hip_runtime.h>
#include <stdint.h>

#define NB 16
#define NC 512
#define NHW 4096

typedef unsigned short u16;
typedef __bf16 bf16x8 __attribute__((ext_vector_type(8)));
typedef float f32x4 __attribute__((ext_vector_type(4)));
typedef unsigned short u16x8 __attribute__((ext_vector_type(8)));
typedef unsigned short u16x4 __attribute__((ext_vector_type(4)));

#define AS1 __attribute__((address_space(1)))
#define AS3 __attribute__((address_space(3)))

__device__ __forceinline__ float bf2f(u16 h) {
    union { unsigned u; float f; } a; a.u = ((unsigned)h) << 16; return a.f;
}
__device__ __forceinline__ u16 f2bf(float f) {
    union { float f; unsigned u; } a; a.f = f;
    unsigned u = a.u;
    return (u16)((u + 0x7FFFu + ((u >> 16) & 1u)) >> 16);  // RNE
}

// ---------------- K0: fp32 -> bf16 copy of x ----------------
__global__ __launch_bounds__(256) void k_to_bf16(const float* __restrict__ x,
                                                 u16* __restrict__ xb) {
    int i = blockIdx.x * 256 + threadIdx.x;
    f32x4 v = ((const f32x4*)x)[i];
    u16x4 o;
    o[0] = f2bf(v[0]); o[1] = f2bf(v[1]); o[2] = f2bf(v[2]); o[3] = f2bf(v[3]);
    ((u16x4*)xb)[i] = o;
}

// ---------------- K1: batched C = scale * A * B^T (bf16 in, bf16 out) ------
// 64x128 tile (was 128x128): grid = (M/64, N/128, NB) = 512 blocks -> 2
// blocks/CU (was 256 = 1/CU, latency-bound: MfmaUtil 15.7%, HBM 27%, occ 10%).
// BK=32, 256 threads (4 waves; each wave owns a 64x32 output slice, acc[4][2]).
// 2-phase double-buffered LDS: stage next BK before computing current; the
// implicit vmcnt(0)-drain of __syncthreads() covers in-flight global_load_lds.
__global__ __launch_bounds__(256, 2)
void k_gemm_bt(const u16* __restrict__ Ab, const u16* __restrict__ Bb,
               u16* __restrict__ Cb, int K, int N,
               size_t sA, size_t sB, size_t sC, float scale) {
    __shared__ u16 As[2][64 * 32];   // 2 x 4 KB
    __shared__ u16 Bs[2][128 * 32];  // 2 x 8 KB   (24 KB total; 2 blocks/CU ok)
    const int tid = threadIdx.x;
    const int wave = tid >> 6, lane = tid & 63;
    const int b = blockIdx.z;
    const u16* A  = Ab + (size_t)b * sA + (size_t)blockIdx.x * 64 * K;
    const u16* Bm = Bb + (size_t)b * sB + (size_t)blockIdx.y * 128 * K;

    // staging addresses: 256 threads cover 64 rows x 32 cols (u16) per tile;
    // LDS dest is wave-uniform base + lane*16B (flat row-major [rows][32]).
    const int srow = tid >> 2;
    const int scol = (tid & 3) * 8;
    const u16* ag0 = A  + (size_t)srow * K + scol;   // A rows 0..63
    const u16* bg0 = Bm + (size_t)srow * K + scol;   // B rows 0..63
    const u16* bg1 = bg0 + (size_t)64 * K;           // B rows 64..127

#define STAGE(BUF, KO)                                                         \
    {                                                                          \
        __builtin_amdgcn_global_load_lds((AS1 void*)(ag0 + (KO)),              \
            (AS3 void*)(&As[BUF][wave * 512]), 16, 0, 0);                      \
        __builtin_amdgcn_global_load_lds((AS1 void*)(bg0 + (KO)),              \
            (AS3 void*)(&Bs[BUF][wave * 512]), 16, 0, 0);                      \
        __builtin_amdgcn_global_load_lds((AS1 void*)(bg1 + (KO)),              \
            (AS3 void*)(&Bs[BUF][2048 + wave * 512]), 16, 0, 0);               \
    }

    f32x4 acc[4][2];
#pragma unroll
    for (int i = 0; i < 4; i++)
#pragma unroll
        for (int j = 0; j < 2; j++) acc[i][j] = f32x4{0.f, 0.f, 0.f, 0.f};

    const int cn = wave * 32;            // wave's column base within the N-tile
    const int m16 = lane & 15, quad = lane >> 4;

#define COMPUTE(BUF)                                                           \
    {                                                                          \
        bf16x8 af[4], bfr[2];                                                  \
        _Pragma("unroll")                                                      \
        for (int mi = 0; mi < 4; mi++)                                         \
            af[mi] = *(const bf16x8*)&As[BUF][(mi * 16 + m16) * 32 +           \
                                             quad * 8];                        \
        _Pragma("unroll")                                                      \
        for (int ni = 0; ni < 2; ni++)                                         \
            bfr[ni] = *(const bf16x8*)&Bs[BUF][(cn + ni * 16 + m16) * 32 +     \
                                              quad * 8];                       \
        _Pragma("unroll")                                                      \
        for (int mi = 0; mi < 4; mi++)                                         \
            _Pragma("unroll")                                                  \
            for (int ni = 0; ni < 2; ni++)                                     \
                acc[mi][ni] = __builtin_amdgcn_mfma_f32_16x16x32_bf16(         \
                    af[mi], bfr[ni], acc[mi][ni], 0, 0, 0);                    \
    }

    // prologue: fill buffer 0 (K is a multiple of 64 for both call sites)
    STAGE(0, 0);
    __syncthreads();

    for (int k0 = 0; k0 < K; k0 += 64) {
        STAGE(1, k0 + 32);      // always in-bounds: k0+32 <= K-32
        COMPUTE(0);
        __syncthreads();        // buf1 ready; all waves done reading buf0
        if (k0 + 64 < K) STAGE(0, k0 + 64);
        COMPUTE(1);
        __syncthreads();        // buf0 ready; all waves done reading buf1
    }

    // C/D layout: col = lane&15, row = (lane>>4)*4 + reg  (m89-verified)
    u16* Co = Cb + (size_t)b * sC + ((size_t)blockIdx.x * 64) * N +
              (size_t)blockIdx.y * 128;
    const int rq = quad * 4;
#pragma unroll
    for (int mi = 0; mi < 4; mi++)
#pragma unroll
        for (int ni = 0; ni < 2; ni++)
#pragma unroll
            for (int r = 0; r < 4; r++) {
                int row = mi * 16 + rq + r;
                int col = cn + ni * 16 + m16;
                Co[(size_t)row * N + col] = f2bf(acc[mi][ni][r] * scale);
            }
#undef STAGE
#undef COMPUTE
}

// ---------------- K2: power iteration (one block per batch) ----------------
// vhat dir = (S2)^5 v0 = S^10 v0 (normalization is pure scaling; S=Ws/4096).
__global__ __launch_bounds__(1024, 1)
void k_power_iter(const u16* __restrict__ S2, const float* __restrict__ v0,
                  float* __restrict__ vhat) {
    const int b = blockIdx.x, tid = threadIdx.x;
    __shared__ float va[NC], vb[NC];
    __shared__ float part[NC][16];   // 32 KB
    __shared__ float red[16];
    const u16* Mb = S2 + (size_t)b * NC * NC;
    const int cg = tid & 15;   // col group: cols cg*8 + p*128 + j (p=0..3)
    const int r0 = tid >> 4;   // row-in-pass (0..63)
    if (tid < NC) va[tid] = v0[b * NC + tid];
    float* cur = va;
    float* nxt = vb;
    __syncthreads();

    for (int it = 0; it < 5; ++it) {
        float c[4][8];
#pragma unroll
        for (int p = 0; p < 4; p++) {
            f32x4 lo = *(const f32x4*)&cur[cg * 8 + p * 128];
            f32x4 hi = *(const f32x4*)&cur[cg * 8 + p * 128 + 4];
            c[p][0] = lo[0]; c[p][1] = lo[1]; c[p][2] = lo[2]; c[p][3] = lo[3];
            c[p][4] = hi[0]; c[p][5] = hi[1]; c[p][6] = hi[2]; c[p][7] = hi[3];
        }
#pragma unroll 2
        for (int pass = 0; pass < 8; ++pass) {
            const int r = pass * 64 + r0;
            const u16* row = Mb + (size_t)r * NC + cg * 8;
            u16x8 m[4];
#pragma unroll
            for (int p = 0; p < 4; p++) m[p] = *(const u16x8*)(row + p * 128);
            float a0 = 0.f, a1 = 0.f, a2 = 0.f, a3 = 0.f;
#pragma unroll
            for (int j = 0; j < 8; j++) {
                a0 += bf2f(m[0][j]) * c[0][j];
                a1 += bf2f(m[1][j]) * c[1][j];
                a2 += bf2f(m[2][j]) * c[2][j];
                a3 += bf2f(m[3][j]) * c[3][j];
            }
            part[r][cg] = (a0 + a1) + (a2 + a3);
        }
        __syncthreads();
        if (tid < NC) {
            f32x4 s0 = *(const f32x4*)&part[tid][0];
            f32x4 s1 = *(const f32x4*)&part[tid][4];
            f32x4 s2 = *(const f32x4*)&part[tid][8];
            f32x4 s3 = *(const f32x4*)&part[tid][12];
            f32x4 s = (s0 + s1) + (s2 + s3);
            nxt[tid] = (s[0] + s[1]) + (s[2] + s[3]);
        }
        __syncthreads();
        float* t = cur; cur = nxt; nxt = t;
    }

    // normalize v10 -> vhat
    float mv = (tid < NC) ? cur[tid] : 0.f;
    float x = mv * mv;
#pragma unroll
    for (int o = 32; o > 0; o >>= 1) x += __shfl_down(x, o, 64);
    if ((tid & 63) == 0) red[tid >> 6] = x;
    __syncthreads();
    float n = red[0];
#pragma unroll
    for (int w = 1; w < 16; w++) n += red[w];
    if (tid < NC) vhat[b * NC + tid] = mv * rsqrtf(n);
}

// ---------------- K3: t[n] = sum_c xb[b][c][n] * vhat[b][c]  (c-split x4) ---
__global__ __launch_bounds__(256)
void k_compute_t(const u16* __restrict__ xb, const float* __restrict__ vhat,
                 float* __restrict__ tp) {
    const int b = blockIdx.z, cc = blockIdx.y, nc = blockIdx.x, tid = threadIdx.x;
    __shared__ float vsh[128];
    if (tid < 128) vsh[tid] = vhat[b * NC + cc * 128 + tid];
    __syncthreads();
    const int n0 = nc * 2048 + tid * 8;
    const u16* xp = xb + (size_t)b * NC * NHW + (size_t)cc * 128 * NHW + n0;
    float acc[8] = {0.f, 0.f, 0.f, 0.f, 0.f, 0.f, 0.f, 0.f};
    for (int c = 0; c < 128; c++) {
        u16x8 w = *(const u16x8*)xp;
        xp += NHW;
        float vc = vsh[c];
#pragma unroll
        for (int j = 0; j < 8; j++) acc[j] += bf2f(w[j]) * vc;
    }
    float* dst = tp + (size_t)(b * 4 + cc) * NHW + n0;
    *(f32x4*)dst       = f32x4{acc[0], acc[1], acc[2], acc[3]};
    *(f32x4*)(dst + 4) = f32x4{acc[4], acc[5], acc[6], acc[7]};
}

// ---------------- K3b: tsum = sum_p tp; sinv = 1/||tsum|| (u-norm) ---------
// s = ||X^T vhat|| = ||t||_2, so no extra matvec is needed for the u-norm.
__global__ __launch_bounds__(1024, 1)
void k_tnorm(const float* __restrict__ tp, float* __restrict__ tsum,
             float* __restrict__ sinv) {
    const int b = blockIdx.x, tid = threadIdx.x;
    __shared__ float red[16];
    const int n0 = tid * 4;  // 1024 threads x 4 = 4096
    f32x4 s = f32x4{0.f, 0.f, 0.f, 0.f};
#pragma unroll
    for (int p = 0; p < 4; p++)
        s += *(const f32x4*)(tp + (size_t)(b * 4 + p) * NHW + n0);
    *(f32x4*)(tsum + (size_t)b * NHW + n0) = s;
    float ss = s[0] * s[0] + s[1] * s[1] + s[2] * s[2] + s[3] * s[3];
#pragma unroll
    for (int o = 32; o > 0; o >>= 1) ss += __shfl_down(ss, o, 64);
    if ((tid & 63) == 0) red[tid >> 6] = ss;
    __syncthreads();
    if (tid == 0) {
        float n = red[0];
#pragma unroll
        for (int w = 1; w < 16; w++) n += red[w];
        sinv[b] = rsqrtf(n);
    }
}

// ---------------- K4: out = x + tsum[n] * (vhat[c] * sinv[b]) ----------------
__global__ __launch_bounds__(256)
void k_epilogue(const float* __restrict__ x, const float* __restrict__ tsum,
                const float* __restrict__ vhat, const float* __restrict__ sinv,
                float* __restrict__ out) {
    const int b = blockIdx.z, cc = blockIdx.y, nc = blockIdx.x, tid = threadIdx.x;
    __shared__ float tl[1024];
    __shared__ float cf[64];
    const int nbase = nc * 1024, cbase = cc * 64;
    const float si = sinv[b];
    for (int i = tid; i < 1024; i += 256)
        tl[i] = tsum[(size_t)b * NHW + nbase + i];
    if (tid < 64) cf[tid] = vhat[b * NC + cbase + tid] * si;
    __syncthreads();
    f32x4 tv = ((const f32x4*)tl)[tid];
    for (int rr = 0; rr < 64; rr++) {
        size_t off = ((size_t)(b * NC + cbase + rr)) * NHW + nbase + tid * 4;
        f32x4 xv = *(const f32x4*)(x + off);
        float c = cf[rr];
        f32x4 o = xv + tv * c;
        *(f32x4*)(out + off) = o;
    }
}

extern "C" void kernel_launch(void* const* d_in, const int* in_sizes, int n_in,
                              void* d_out, int out_size, void* d_ws, size_t ws_size,
                              hipStream_t stream) {
    const float* x  = (const float*)d_in[0];   // (16,512,64,64) fp32
    const float* v0 = (const float*)d_in[1];   // (16,512,1) fp32
    float* out = (float*)d_out;

    char* ws = (char*)d_ws;
    u16* xb     = (u16*)ws;                                   // 64 MiB bf16 x
    u16* S      = (u16*)(ws + 67108864);                      // 8 MiB  Ws/4096
    u16* S2     = (u16*)(ws + 67108864 + 8388608);            // 8 MiB  S^2
    float* vhat = (float*)(ws + 83886080);                    // 32 KiB
    float* tp   = (float*)(ws + 83886080 + 65536);            // 1 MiB (4 c-partials)
    float* tsum = (float*)(ws + 83886080 + 65536 + 1048576);  // 256 KiB
    float* sinv = (float*)(ws + 83886080 + 65536 + 1048576 + 262144);  // 64 B

    k_to_bf16<<<dim3(32768), dim3(256), 0, stream>>>(x, xb);
    // S = (X X^T) / 4096   (M=N=512, K=4096) — 64x128 tiles, 512 blocks
    k_gemm_bt<<<dim3(8, 4, NB), dim3(256), 0, stream>>>(
        xb, xb, S, NHW, NC, (size_t)NC * NHW, (size_t)NC * NHW, (size_t)NC * NC,
        1.f / 4096.f);
    // S2 = S * S^T = S * S   (M=N=K=512, S symmetric)
    k_gemm_bt<<<dim3(8, 4, NB), dim3(256), 0, stream>>>(
        S, S, S2, NC, NC, (size_t)NC * NC, (size_t)NC * NC, (size_t)NC * NC,
        1.f);
    k_power_iter<<<dim3(NB), dim3(1024), 0, stream>>>(S2, v0, vhat);
    k_compute_t<<<dim3(2, 4, NB), dim3(256), 0, stream>>>(xb, vhat, tp);
    k_tnorm<<<dim3(NB), dim3(1024), 0, stream>>>(tp, tsum, sinv);
    k_epilogue<<<dim3(4, 8, NB), dim3(256), 0, stream>>>(x, tsum, vhat, sinv, out);
}

// Round 4
// 395.007 us; speedup vs baseline: 1.0399x; 1.0399x over previous
//
#include <hip/hip_runtime.h>
#include <stdint.h>

#define NB 16
#define NC 512
#define NHW 4096

typedef unsigned short u16;
typedef __bf16 bf16x8 __attribute__((ext_vector_type(8)));
typedef float f32x4 __attribute__((ext_vector_type(4)));
typedef unsigned short u16x8 __attribute__((ext_vector_type(8)));
typedef unsigned short u16x4 __attribute__((ext_vector_type(4)));

#define AS1 __attribute__((address_space(1)))
#define AS3 __attribute__((address_space(3)))

__device__ __forceinline__ float bf2f(u16 h) {
    union { unsigned u; float f; } a; a.u = ((unsigned)h) << 16; return a.f;
}
__device__ __forceinline__ u16 f2bf(float f) {
    union { float f; unsigned u; } a; a.f = f;
    unsigned u = a.u;
    return (u16)((u + 0x7FFFu + ((u >> 16) & 1u)) >> 16);  // RNE
}

// ---------------- K0: fp32 -> bf16 copy of x ----------------
__global__ __launch_bounds__(256) void k_to_bf16(const float* __restrict__ x,
                                                 u16* __restrict__ xb) {
    int i = blockIdx.x * 256 + threadIdx.x;
    f32x4 v = ((const f32x4*)x)[i];
    u16x4 o;
    o[0] = f2bf(v[0]); o[1] = f2bf(v[1]); o[2] = f2bf(v[2]); o[3] = f2bf(v[3]);
    ((u16x4*)xb)[i] = o;
}

// ---------------- K1: batched C = scale * A * B^T (bf16 in, bf16 out) ------
// 128x128 tile, BK=32, 256 threads (4 waves, 2x2 of 64x64), grid 256 = 1
// block/CU. That regime makes the old stage->__syncthreads() loop expose the
// full HBM latency every K-step (vmcnt(0) drain, nothing co-resident to
// overlap). Fix = T4 counted-vmcnt pipeline:
//   * 4-deep LDS ring (4 x 16 KB): 3 K-steps of global_load_lds always in
//     flight; per-phase wait is s_waitcnt vmcnt(12) (oldest stage only),
//     never 0 until the epilogue (12->8->4->0).
//   * raw s_barrier (no implicit drain) + sched_barrier(0) to pin the phase
//     skeleton against compiler reordering (rule #18).
//   * LDS XOR swizzle chunk ^= (row>>1)&3 applied as pre-swizzled GLOBAL
//     source (linear global_load_lds dest, rule #21) + same XOR on ds_read:
//     8-way bank conflict -> 2-way (free).
__global__ __launch_bounds__(256, 1)
void k_gemm_bt(const u16* __restrict__ Ab, const u16* __restrict__ Bb,
               u16* __restrict__ Cb, int K, int N,
               size_t sA, size_t sB, size_t sC, float scale) {
    __shared__ u16 As[4][128 * 32];  // 4 x 8 KB
    __shared__ u16 Bs[4][128 * 32];  // 4 x 8 KB  (64 KB total)
    const int tid = threadIdx.x;
    const int wave = tid >> 6, lane = tid & 63;
    const int b = blockIdx.z;
    const u16* A  = Ab + (size_t)b * sA + (size_t)blockIdx.x * 128 * K;
    const u16* Bm = Bb + (size_t)b * sB + (size_t)blockIdx.y * 128 * K;

    // Staging: 256 threads x 16 B cover 64 rows x 32 cols per load; 2 loads
    // per matrix per K-step. LDS dest is linear (HW: wave base + lane*16B),
    // so the bank swizzle is applied by permuting the GLOBAL source column:
    // LDS[row][chunk] <- global[row][chunk ^ ((row>>1)&3)]   (chunk = 16B unit)
    const int srow = tid >> 2;                       // 0..63
    const int scol = ((tid & 3) ^ ((srow >> 1) & 3)) * 8;   // swizzled u16 col
    const u16* ag0 = A  + (size_t)srow * K + scol;
    const u16* ag1 = ag0 + (size_t)64 * K;           // row+64: same low bits
    const u16* bg0 = Bm + (size_t)srow * K + scol;
    const u16* bg1 = bg0 + (size_t)64 * K;

#define STAGE(BUF, KO)                                                         \
    {                                                                          \
        __builtin_amdgcn_global_load_lds((AS1 void*)(ag0 + (KO)),              \
            (AS3 void*)(&As[BUF][wave * 512]), 16, 0, 0);                      \
        __builtin_amdgcn_global_load_lds((AS1 void*)(ag1 + (KO)),              \
            (AS3 void*)(&As[BUF][2048 + wave * 512]), 16, 0, 0);               \
        __builtin_amdgcn_global_load_lds((AS1 void*)(bg0 + (KO)),              \
            (AS3 void*)(&Bs[BUF][wave * 512]), 16, 0, 0);                      \
        __builtin_amdgcn_global_load_lds((AS1 void*)(bg1 + (KO)),              \
            (AS3 void*)(&Bs[BUF][2048 + wave * 512]), 16, 0, 0);               \
    }

    f32x4 acc[4][4];
#pragma unroll
    for (int i = 0; i < 4; i++)
#pragma unroll
        for (int j = 0; j < 4; j++) acc[i][j] = f32x4{0.f, 0.f, 0.f, 0.f};

    const int rm = (wave & 1) * 64;
    const int rn = (wave >> 1) * 64;
    const int m16 = lane & 15, quad = lane >> 4;
    // read-side swizzle: logical chunk 'quad' of row R lives at chunk
    // quad ^ ((R>>1)&3); (R>>1)&3 == (m16>>1)&3 for all fragment rows.
    const int qsw8 = (quad ^ ((m16 >> 1) & 3)) * 8;

#define COMPUTE(BUF)                                                           \
    {                                                                          \
        bf16x8 af[4], bfr[4];                                                  \
        _Pragma("unroll")                                                      \
        for (int mi = 0; mi < 4; mi++)                                         \
            af[mi] = *(const bf16x8*)&As[BUF][(rm + mi * 16 + m16) * 32 +      \
                                             qsw8];                            \
        _Pragma("unroll")                                                      \
        for (int ni = 0; ni < 4; ni++)                                         \
            bfr[ni] = *(const bf16x8*)&Bs[BUF][(rn + ni * 16 + m16) * 32 +     \
                                              qsw8];                           \
        _Pragma("unroll")                                                      \
        for (int mi = 0; mi < 4; mi++)                                         \
            _Pragma("unroll")                                                  \
            for (int ni = 0; ni < 4; ni++)                                     \
                acc[mi][ni] = __builtin_amdgcn_mfma_f32_16x16x32_bf16(         \
                    af[mi], bfr[ni], acc[mi][ni], 0, 0, 0);                    \
    }

// Phase: wait own oldest stage (buffer J) -> barrier (all waves' chunks in)
// -> compute J -> barrier (all waves done reading J) -> re-stage J.
// vmcnt(12): 4 stages x 4 loads = 16 outstanding; oldest 4 = buffer J.
#define PHASE(J, KNEXT)                                                        \
    asm volatile("s_waitcnt vmcnt(12)" ::: "memory");                          \
    __builtin_amdgcn_s_barrier();                                              \
    __builtin_amdgcn_sched_barrier(0);                                         \
    COMPUTE(J);                                                                \
    __builtin_amdgcn_sched_barrier(0);                                         \
    __builtin_amdgcn_s_barrier();                                              \
    STAGE(J, KNEXT);

    // prologue: fill the 4-deep ring (K >= 128 always: K is 512 or 4096)
    STAGE(0, 0);
    STAGE(1, 32);
    STAGE(2, 64);
    STAGE(3, 96);

    // main: each group computes steps kg..kg+96, stages kg+128..kg+224
    for (int kg = 0; kg + 256 <= K; kg += 128) {
        PHASE(0, kg + 128);
        PHASE(1, kg + 160);
        PHASE(2, kg + 192);
        PHASE(3, kg + 224);
    }

    // epilogue: last 4 steps, draining 12 -> 8 -> 4 -> 0
    asm volatile("s_waitcnt vmcnt(12)" ::: "memory");
    __builtin_amdgcn_s_barrier();
    __builtin_amdgcn_sched_barrier(0);
    COMPUTE(0);
    asm volatile("s_waitcnt vmcnt(8)" ::: "memory");
    __builtin_amdgcn_s_barrier();
    __builtin_amdgcn_sched_barrier(0);
    COMPUTE(1);
    asm volatile("s_waitcnt vmcnt(4)" ::: "memory");
    __builtin_amdgcn_s_barrier();
    __builtin_amdgcn_sched_barrier(0);
    COMPUTE(2);
    asm volatile("s_waitcnt vmcnt(0)" ::: "memory");
    __builtin_amdgcn_s_barrier();
    __builtin_amdgcn_sched_barrier(0);
    COMPUTE(3);

    // C/D layout: col = lane&15, row = (lane>>4)*4 + reg  (m89-verified)
    u16* Co = Cb + (size_t)b * sC + ((size_t)blockIdx.x * 128) * N +
              (size_t)blockIdx.y * 128;
    const int rq = quad * 4;
#pragma unroll
    for (int mi = 0; mi < 4; mi++)
#pragma unroll
        for (int ni = 0; ni < 4; ni++)
#pragma unroll
            for (int r = 0; r < 4; r++) {
                int row = rm + mi * 16 + rq + r;
                int col = rn + ni * 16 + m16;
                Co[(size_t)row * N + col] = f2bf(acc[mi][ni][r] * scale);
            }
#undef STAGE
#undef COMPUTE
#undef PHASE
}

// ---------------- K2: power iteration (one block per batch) ----------------
// vhat dir = (S2)^5 v0 = S^10 v0 (normalization is pure scaling; S=Ws/4096).
__global__ __launch_bounds__(1024, 1)
void k_power_iter(const u16* __restrict__ S2, const float* __restrict__ v0,
                  float* __restrict__ vhat) {
    const int b = blockIdx.x, tid = threadIdx.x;
    __shared__ float va[NC], vb[NC];
    __shared__ float part[NC][16];   // 32 KB
    __shared__ float red[16];
    const u16* Mb = S2 + (size_t)b * NC * NC;
    const int cg = tid & 15;   // col group: cols cg*8 + p*128 + j (p=0..3)
    const int r0 = tid >> 4;   // row-in-pass (0..63)
    if (tid < NC) va[tid] = v0[b * NC + tid];
    float* cur = va;
    float* nxt = vb;
    __syncthreads();

    for (int it = 0; it < 5; ++it) {
        float c[4][8];
#pragma unroll
        for (int p = 0; p < 4; p++) {
            f32x4 lo = *(const f32x4*)&cur[cg * 8 + p * 128];
            f32x4 hi = *(const f32x4*)&cur[cg * 8 + p * 128 + 4];
            c[p][0] = lo[0]; c[p][1] = lo[1]; c[p][2] = lo[2]; c[p][3] = lo[3];
            c[p][4] = hi[0]; c[p][5] = hi[1]; c[p][6] = hi[2]; c[p][7] = hi[3];
        }
#pragma unroll 2
        for (int pass = 0; pass < 8; ++pass) {
            const int r = pass * 64 + r0;
            const u16* row = Mb + (size_t)r * NC + cg * 8;
            u16x8 m[4];
#pragma unroll
            for (int p = 0; p < 4; p++) m[p] = *(const u16x8*)(row + p * 128);
            float a0 = 0.f, a1 = 0.f, a2 = 0.f, a3 = 0.f;
#pragma unroll
            for (int j = 0; j < 8; j++) {
                a0 += bf2f(m[0][j]) * c[0][j];
                a1 += bf2f(m[1][j]) * c[1][j];
                a2 += bf2f(m[2][j]) * c[2][j];
                a3 += bf2f(m[3][j]) * c[3][j];
            }
            part[r][cg] = (a0 + a1) + (a2 + a3);
        }
        __syncthreads();
        if (tid < NC) {
            f32x4 s0 = *(const f32x4*)&part[tid][0];
            f32x4 s1 = *(const f32x4*)&part[tid][4];
            f32x4 s2 = *(const f32x4*)&part[tid][8];
            f32x4 s3 = *(const f32x4*)&part[tid][12];
            f32x4 s = (s0 + s1) + (s2 + s3);
            nxt[tid] = (s[0] + s[1]) + (s[2] + s[3]);
        }
        __syncthreads();
        float* t = cur; cur = nxt; nxt = t;
    }

    // normalize v10 -> vhat
    float mv = (tid < NC) ? cur[tid] : 0.f;
    float x = mv * mv;
#pragma unroll
    for (int o = 32; o > 0; o >>= 1) x += __shfl_down(x, o, 64);
    if ((tid & 63) == 0) red[tid >> 6] = x;
    __syncthreads();
    float n = red[0];
#pragma unroll
    for (int w = 1; w < 16; w++) n += red[w];
    if (tid < NC) vhat[b * NC + tid] = mv * rsqrtf(n);
}

// ---------------- K3: t[n] = sum_c xb[b][c][n] * vhat[b][c]  (c-split x4) ---
__global__ __launch_bounds__(256)
void k_compute_t(const u16* __restrict__ xb, const float* __restrict__ vhat,
                 float* __restrict__ tp) {
    const int b = blockIdx.z, cc = blockIdx.y, nc = blockIdx.x, tid = threadIdx.x;
    __shared__ float vsh[128];
    if (tid < 128) vsh[tid] = vhat[b * NC + cc * 128 + tid];
    __syncthreads();
    const int n0 = nc * 2048 + tid * 8;
    const u16* xp = xb + (size_t)b * NC * NHW + (size_t)cc * 128 * NHW + n0;
    float acc[8] = {0.f, 0.f, 0.f, 0.f, 0.f, 0.f, 0.f, 0.f};
    for (int c = 0; c < 128; c++) {
        u16x8 w = *(const u16x8*)xp;
        xp += NHW;
        float vc = vsh[c];
#pragma unroll
        for (int j = 0; j < 8; j++) acc[j] += bf2f(w[j]) * vc;
    }
    float* dst = tp + (size_t)(b * 4 + cc) * NHW + n0;
    *(f32x4*)dst       = f32x4{acc[0], acc[1], acc[2], acc[3]};
    *(f32x4*)(dst + 4) = f32x4{acc[4], acc[5], acc[6], acc[7]};
}

// ---------------- K3b: tsum = sum_p tp; sinv = 1/||tsum|| (u-norm) ---------
// s = ||X^T vhat|| = ||t||_2, so no extra matvec is needed for the u-norm.
__global__ __launch_bounds__(1024, 1)
void k_tnorm(const float* __restrict__ tp, float* __restrict__ tsum,
             float* __restrict__ sinv) {
    const int b = blockIdx.x, tid = threadIdx.x;
    __shared__ float red[16];
    const int n0 = tid * 4;  // 1024 threads x 4 = 4096
    f32x4 s = f32x4{0.f, 0.f, 0.f, 0.f};
#pragma unroll
    for (int p = 0; p < 4; p++)
        s += *(const f32x4*)(tp + (size_t)(b * 4 + p) * NHW + n0);
    *(f32x4*)(tsum + (size_t)b * NHW + n0) = s;
    float ss = s[0] * s[0] + s[1] * s[1] + s[2] * s[2] + s[3] * s[3];
#pragma unroll
    for (int o = 32; o > 0; o >>= 1) ss += __shfl_down(ss, o, 64);
    if ((tid & 63) == 0) red[tid >> 6] = ss;
    __syncthreads();
    if (tid == 0) {
        float n = red[0];
#pragma unroll
        for (int w = 1; w < 16; w++) n += red[w];
        sinv[b] = rsqrtf(n);
    }
}

// ---------------- K4: out = x + tsum[n] * (vhat[c] * sinv[b]) ----------------
__global__ __launch_bounds__(256)
void k_epilogue(const float* __restrict__ x, const float* __restrict__ tsum,
                const float* __restrict__ vhat, const float* __restrict__ sinv,
                float* __restrict__ out) {
    const int b = blockIdx.z, cc = blockIdx.y, nc = blockIdx.x, tid = threadIdx.x;
    __shared__ float tl[1024];
    __shared__ float cf[64];
    const int nbase = nc * 1024, cbase = cc * 64;
    const float si = sinv[b];
    for (int i = tid; i < 1024; i += 256)
        tl[i] = tsum[(size_t)b * NHW + nbase + i];
    if (tid < 64) cf[tid] = vhat[b * NC + cbase + tid] * si;
    __syncthreads();
    f32x4 tv = ((const f32x4*)tl)[tid];
    for (int rr = 0; rr < 64; rr++) {
        size_t off = ((size_t)(b * NC + cbase + rr)) * NHW + nbase + tid * 4;
        f32x4 xv = *(const f32x4*)(x + off);
        float c = cf[rr];
        f32x4 o = xv + tv * c;
        *(f32x4*)(out + off) = o;
    }
}

extern "C" void kernel_launch(void* const* d_in, const int* in_sizes, int n_in,
                              void* d_out, int out_size, void* d_ws, size_t ws_size,
                              hipStream_t stream) {
    const float* x  = (const float*)d_in[0];   // (16,512,64,64) fp32
    const float* v0 = (const float*)d_in[1];   // (16,512,1) fp32
    float* out = (float*)d_out;

    char* ws = (char*)d_ws;
    u16* xb     = (u16*)ws;                                   // 64 MiB bf16 x
    u16* S      = (u16*)(ws + 67108864);                      // 8 MiB  Ws/4096
    u16* S2     = (u16*)(ws + 67108864 + 8388608);            // 8 MiB  S^2
    float* vhat = (float*)(ws + 83886080);                    // 32 KiB
    float* tp   = (float*)(ws + 83886080 + 65536);            // 1 MiB (4 c-partials)
    float* tsum = (float*)(ws + 83886080 + 65536 + 1048576);  // 256 KiB
    float* sinv = (float*)(ws + 83886080 + 65536 + 1048576 + 262144);  // 64 B

    k_to_bf16<<<dim3(32768), dim3(256), 0, stream>>>(x, xb);
    // S = (X X^T) / 4096   (M=N=512, K=4096) — 128x128 tiles
    k_gemm_bt<<<dim3(4, 4, NB), dim3(256), 0, stream>>>(
        xb, xb, S, NHW, NC, (size_t)NC * NHW, (size_t)NC * NHW, (size_t)NC * NC,
        1.f / 4096.f);
    // S2 = S * S^T = S * S   (M=N=K=512, S symmetric)
    k_gemm_bt<<<dim3(4, 4, NB), dim3(256), 0, stream>>>(
        S, S, S2, NC, NC, (size_t)NC * NC, (size_t)NC * NC, (size_t)NC * NC,
        1.f);
    k_power_iter<<<dim3(NB), dim3(1024), 0, stream>>>(S2, v0, vhat);
    k_compute_t<<<dim3(2, 4, NB), dim3(256), 0, stream>>>(xb, vhat, tp);
    k_tnorm<<<dim3(NB), dim3(1024), 0, stream>>>(tp, tsum, sinv);
    k_epilogue<<<dim3(4, 8, NB), dim3(256), 0, stream>>>(x, tsum, vhat, sinv, out);
}